// Round 1
// baseline (73.489 us; speedup 1.0000x reference)
//
#include <hip/hip_runtime.h>

// ChamferDistanceMatrixL2: B=32, G=64, N=32, C=3.
// out[b][g1][g2] = mean_n min_m d(n,m) + mean_m min_n d(n,m),
// d(n,m) = s1 + s2 - 2*dot.
//
// v2: m-split 2-way across lane halves. lane = (half<<5)|g2lo; partner
// lane^32 handles the other 16 points of the same g2 group. Register
// arrays halve (qx/qy/qz/s2[16] + colmin[16] ~= 110 VGPR) -> 4 waves/SIMD
// (was 2 @ ~190 VGPR). 4096 waves = exactly 4/SIMD, one residency round.
// p1 offset is readfirstlane'd so the per-n loads become s_load from
// K$ with compile-time offsets (no vmcnt waits in the n-loop).
// rmin update written as fminf(fminf(t0,t1),rmin) to fuse into v_min3_f32.
// Per-n cross-half combine: one __shfl_xor(rmin, 32) + fmin.

__global__ __launch_bounds__(256, 4)
void chamfer_dist_kernel(const float* __restrict__ xyz1,
                         const float* __restrict__ xyz2,
                         float* __restrict__ out) {
    const int b    = blockIdx.x >> 5;           // 0..31
    const int pair = blockIdx.x & 31;           // g1 pair index
    const int wave = threadIdx.x >> 6;          // 0..3
    const int lane = threadIdx.x & 63;
    const int g1   = (pair << 1) | (wave >> 1); // 0..63, wave-uniform
    const int g2   = ((wave & 1) << 5) | (lane & 31); // 0..63
    const int half = lane >> 5;                 // which 16-point m-half

    // ---- register-cache this thread's 16 points of group g2 ----
    // q = -2*p2, s2 = |p2|^2. 16 pts * 3 floats = 48 floats = 12 float4
    // (offsets 384B*(b*64+g2) + 192B*half -> 16B aligned).
    const float* __restrict__ p2 =
        xyz2 + (size_t)(b * 64 + g2) * 96 + half * 48;
    const float4* __restrict__ p2v = reinterpret_cast<const float4*>(p2);

    float qx[16], qy[16], qz[16], s2[16], colmin[16];
#pragma unroll
    for (int i = 0; i < 4; ++i) {
        const float4 va = p2v[3 * i + 0];
        const float4 vb = p2v[3 * i + 1];
        const float4 vc = p2v[3 * i + 2];
        const float f[12] = {va.x, va.y, va.z, va.w,
                             vb.x, vb.y, vb.z, vb.w,
                             vc.x, vc.y, vc.z, vc.w};
#pragma unroll
        for (int j = 0; j < 4; ++j) {
            const int m = 4 * i + j;
            const float x = f[3 * j + 0];
            const float y = f[3 * j + 1];
            const float z = f[3 * j + 2];
            s2[m] = fmaf(x, x, fmaf(y, y, z * z));
            qx[m] = -2.0f * x;
            qy[m] = -2.0f * y;
            qz[m] = -2.0f * z;
            colmin[m] = 3.0e38f;
        }
    }

    // ---- wave-uniform p1 pointer -> scalar loads from K$ ----
    const int off1 = __builtin_amdgcn_readfirstlane((b * 64 + g1) * 96);
    const float* __restrict__ p1 = xyz1 + off1;

    float sum1 = 0.0f;

#pragma unroll 4
    for (int n = 0; n < 32; ++n) {
        const float x1 = p1[3 * n + 0];   // uniform -> s_load, const offset
        const float y1 = p1[3 * n + 1];
        const float z1 = p1[3 * n + 2];
        const float s1 = fmaf(x1, x1, fmaf(y1, y1, z1 * z1));
        float rmin = 3.0e38f;
#pragma unroll
        for (int m = 0; m < 16; m += 2) {
            const float t0 = fmaf(x1, qx[m],
                             fmaf(y1, qy[m],
                             fmaf(z1, qz[m], s1 + s2[m])));
            const float t1 = fmaf(x1, qx[m + 1],
                             fmaf(y1, qy[m + 1],
                             fmaf(z1, qz[m + 1], s1 + s2[m + 1])));
            rmin = fminf(fminf(t0, t1), rmin);      // -> v_min3_f32
            colmin[m]     = fminf(colmin[m], t0);
            colmin[m + 1] = fminf(colmin[m + 1], t1);
        }
        // combine row-min across the two m-halves (partner = lane^32)
        rmin = fminf(rmin, __shfl_xor(rmin, 32, 64));
        sum1 += rmin;
    }

    float sum2 = 0.0f;
#pragma unroll
    for (int m = 0; m < 16; ++m) sum2 += colmin[m];
    sum2 += __shfl_xor(sum2, 32, 64);   // combine col-min sums across halves

    if (half == 0)
        out[(size_t)(b * 64 + g1) * 64 + g2] = (sum1 + sum2) * (1.0f / 32.0f);
}

extern "C" void kernel_launch(void* const* d_in, const int* in_sizes, int n_in,
                              void* d_out, int out_size, void* d_ws, size_t ws_size,
                              hipStream_t stream) {
    const float* xyz1 = (const float*)d_in[0];
    const float* xyz2 = (const float*)d_in[1];
    float* out = (float*)d_out;

    dim3 grid(1024);  // 32 b * 32 g1-pairs
    dim3 block(256);  // 4 waves: 2 g1 * 2 g2-half-blocks; lanes = 32 g2 * 2 m-halves
    chamfer_dist_kernel<<<grid, block, 0, stream>>>(xyz1, xyz2, out);
}